// Round 2
// 11193.408 us; speedup vs baseline: 1.8710x; 1.8710x over previous
//
#include <hip/hip_runtime.h>
#include <hip/hip_fp16.h>

#define BB   32
#define TENC 256
#define EE   512
#define TDEC 200
#define NM   80
#define HH   1024
#define AA   128
#define GG   4096
#define K1   1792   // x(256)|ctx(512)|h1(1024)
#define K2   2048   // h1|h2

typedef _Float16 h8v  __attribute__((ext_vector_type(8)));
typedef float    f32x4 __attribute__((ext_vector_type(4)));

__device__ __forceinline__ float sigf(float x){ return 1.0f/(1.0f + __expf(-x)); }
__device__ __forceinline__ float tanhfast(float x){ return 1.0f - 2.0f/(1.0f + __expf(2.0f*x)); }

// ---------------- precompute kernels ----------------

__global__ void k_zero(float* __restrict__ p, int n){
    int i = blockIdx.x*blockDim.x + threadIdx.x;
    if(i < n) p[i] = 0.f;
}

__global__ void k_cvt_half(const float* __restrict__ src, __half* __restrict__ dst, int n){
    int i = blockIdx.x*blockDim.x + threadIdx.x;
    int stride = gridDim.x*blockDim.x;
    for(; i<n; i+=stride) dst[i] = __float2half(src[i]);
}

// transpose fp32 src[k][c] -> fp16 dst[p][kOff+k]; pack=1 remaps c (gate*1024+cell) -> p=cell*4+gate
__global__ __launch_bounds__(256) void k_transpose2(const float* __restrict__ src,
                                                    _Float16* __restrict__ dst,
                                                    int K, int C, int dstStride, int kOff, int pack){
    __shared__ float tile[32][33];
    const int tid = threadIdx.x;
    const int c0 = blockIdx.x*32, k0 = blockIdx.y*32;
    const int cl = tid & 31, r8 = tid >> 5;
    #pragma unroll
    for(int i=0;i<4;i++){
        const int k = k0 + r8 + i*8;
        if(k < K && c0+cl < C) tile[r8 + i*8][cl] = src[(size_t)k*C + c0 + cl];
    }
    __syncthreads();
    const int kl = tid & 31, c8 = tid >> 5;
    #pragma unroll
    for(int i=0;i<4;i++){
        const int c = c0 + c8 + i*8;
        if(c < C && k0+kl < K){
            const int p = pack ? ((c & 1023)*4 + (c >> 10)) : c;
            dst[(size_t)p*dstStride + kOff + k0 + kl] = (_Float16)tile[kl][c8 + i*8];
        }
    }
}

// Rearrange WT fp16 [P=4096][K] into MFMA B-fragment order:
// WF[((ct*(K/32)+kc)*64 + lane)*8 + i] = WT[(ct*16 + (lane&15))*K + kc*32 + (lane>>4)*8 + i]
// so each wave's B-load per fragment is 64 lanes x contiguous 16B.
__global__ __launch_bounds__(256) void k_wfrag(const _Float16* __restrict__ WT,
                                               _Float16* __restrict__ WF, int K){
    const int tid = threadIdx.x;
    const int l = tid & 63, f = tid >> 6;
    const int ct = blockIdx.y;
    const int kc = blockIdx.x*4 + f;
    const h8v v = *(const h8v*)(WT + (size_t)(ct*16 + (l & 15))*K + kc*32 + ((l >> 4) << 3));
    *(h8v*)(WF + ((size_t)(ct*(K >> 5) + kc)*64 + l)*8) = v;
}

__global__ __launch_bounds__(128) void k_proc_enc(const float* __restrict__ inputs,
                                                  const float* __restrict__ Wenc,
                                                  __half* __restrict__ pe_h){
    const int row = blockIdx.x;
    const int a   = threadIdx.x;
    const float* in = inputs + (size_t)row*EE;
    float acc = 0.f;
    for(int k=0;k<EE;k++) acc = fmaf(in[k], Wenc[k*AA + a], acc);
    pe_h[(size_t)row*AA + a] = __float2half(acc);
}

__global__ __launch_bounds__(320) void k_pip(const float* __restrict__ inputs,
                                             const float* __restrict__ Wp_c,
                                             __half* __restrict__ PIP){
    const int b = blockIdx.x >> 6, t4 = (blockIdx.x & 63)*4;
    __shared__ float xs[4*EE];
    const int tid = threadIdx.x;
    for(int i=tid; i<4*EE; i+=320) xs[i] = inputs[((size_t)b*TENC + t4)*EE + i];
    __syncthreads();
    const int tl = tid/80, m = tid%80;
    float acc = 0.f;
    for(int k=0;k<EE;k++) acc = fmaf(xs[tl*EE + k], Wp_c[k*NM + m], acc);
    PIP[((size_t)b*TENC + t4 + tl)*NM + m] = __float2half(acc);
}

// prenet for all t -> fp16 XS1h rows [t][b][0:256] (row stride K1)
__global__ __launch_bounds__(256) void k_prenet(const float* __restrict__ pmels,
                                                const float* __restrict__ pw1, const float* __restrict__ pb1,
                                                const float* __restrict__ pw2, const float* __restrict__ pb2,
                                                _Float16* __restrict__ XS1h){
    const int t = blockIdx.x;
    __shared__ float pm[BB*NM];
    __shared__ float h1s[BB*256];
    const int tid = threadIdx.x;
    for(int el=tid; el<BB*NM; el+=256){
        const int b = el/NM, m = el%NM;
        pm[el] = (t==0) ? 0.f : pmels[(size_t)(b*NM + m)*TDEC + (t-1)];
    }
    __syncthreads();
    const int a = tid;
    float acc[BB];
    #pragma unroll
    for(int b=0;b<BB;b++) acc[b]=0.f;
    for(int m=0;m<NM;m++){
        const float w = pw1[m*256 + a];
        #pragma unroll
        for(int b=0;b<BB;b++) acc[b] = fmaf(pm[b*NM+m], w, acc[b]);
    }
    {
        const float bias = pb1[a];
        for(int b=0;b<BB;b++) h1s[b*256+a] = fmaxf(acc[b]+bias, 0.f);
    }
    __syncthreads();
    #pragma unroll
    for(int b=0;b<BB;b++) acc[b]=0.f;
    for(int k=0;k<256;k++){
        const float w = pw2[k*256 + a];
        #pragma unroll
        for(int b=0;b<BB;b++) acc[b] = fmaf(h1s[b*256+k], w, acc[b]);
    }
    {
        const float bias = pb2[a];
        #pragma unroll
        for(int b=0;b<BB;b++)
            XS1h[((size_t)t*BB + b)*K1 + a] = (_Float16)fmaxf(acc[b]+bias, 0.f);
    }
}

__global__ void k_mloc(const float* __restrict__ conv_w, const float* __restrict__ conv_b,
                       const float* __restrict__ W_loc, float* __restrict__ Mloc, float* __restrict__ cbp){
    const int a = threadIdx.x;
    for(int d=0; d<31; d++){
        float s = 0.f;
        for(int ch=0; ch<32; ch++) s = fmaf(conv_w[ch*31 + d], W_loc[ch*AA + a], s);
        Mloc[d*AA + a] = s;
    }
    float s = 0.f;
    for(int ch=0; ch<32; ch++) s = fmaf(conv_b[ch], W_loc[ch*AA + a], s);
    cbp[a] = s;
}

// ---------------- per-step kernels ----------------

// MFMA GEMM + LSTM cell. C[32][4096p] = X[32][K](fp16) @ W[K][4096p](fp16 frag layout).
// grid 256 blocks (16 packed cols = 4 cells each), 512 threads = 8 waves:
//   wave w: kw=w&3 (K/4 slice), mh=w>>2 (16-row M-tile). 1 mfma_16x16x32_f16 per kc.
// Cross-wave reduce in LDS, then fused cell nonlinearity; h written fp16 (2 dests) + optional fp32.
template<int K>
__global__ __launch_bounds__(512) void k_lstm_mfma(
    const _Float16* __restrict__ XSh, const _Float16* __restrict__ WF,
    const float* __restrict__ bias, float* __restrict__ cst,
    _Float16* __restrict__ hA, int strideA, int offA,
    _Float16* __restrict__ hB, int strideB, int offB,
    float* __restrict__ hF)
{
    constexpr int KCN = K/128;          // kc iterations per wave
    __shared__ float part[4*32*18];     // [kw][row 0..31][col 0..15 pad 18]
    const int tid = threadIdx.x, bid = blockIdx.x;
    const int l = tid & 63, w = tid >> 6;
    const int kw = w & 3, mh = w >> 2;

    f32x4 acc0 = {0.f,0.f,0.f,0.f}, acc1 = {0.f,0.f,0.f,0.f};
    const int row = mh*16 + (l & 15);
    const _Float16* aptr = XSh + (size_t)row*K + kw*(K/4) + ((l >> 4) << 3);
    const _Float16* bptr = WF + ((size_t)(bid*(K >> 5) + kw*KCN)*64 + l)*8;
    #pragma unroll
    for(int kc=0; kc<KCN; kc+=2){
        const h8v a0 = *(const h8v*)(aptr + (size_t)kc*32);
        const h8v b0 = *(const h8v*)(bptr + (size_t)kc*512);
        const h8v a1 = *(const h8v*)(aptr + (size_t)(kc+1)*32);
        const h8v b1 = *(const h8v*)(bptr + (size_t)(kc+1)*512);
        acc0 = __builtin_amdgcn_mfma_f32_16x16x32_f16(a0, b0, acc0, 0, 0, 0);
        acc1 = __builtin_amdgcn_mfma_f32_16x16x32_f16(a1, b1, acc1, 0, 0, 0);
    }
    // D layout: col = l&15, row(tile) = (l>>4)*4 + j  [measured m89/m91]
    {
        const int r0 = mh*16 + ((l >> 4) << 2);
        const int c  = l & 15;
        #pragma unroll
        for(int j=0;j<4;j++)
            part[(kw*32 + r0 + j)*18 + c] = acc0[j] + acc1[j];
    }
    __syncthreads();
    if(tid < 128){
        const int b = tid & 31, cl = tid >> 5;   // cl: cell-local 0..3
        float g[4];
        #pragma unroll
        for(int gi=0; gi<4; gi++){
            const int c = cl*4 + gi;
            float s = part[(0*32 + b)*18 + c] + part[(1*32 + b)*18 + c]
                    + part[(2*32 + b)*18 + c] + part[(3*32 + b)*18 + c];
            const int p = bid*16 + c;            // packed col = cell*4 + gate
            g[gi] = s + bias[(p & 3)*HH + (p >> 2)];
        }
        const int cell = bid*4 + cl;
        const int ci = cell*BB + b;
        const float cn = sigf(g[1])*cst[ci] + sigf(g[0])*tanhfast(g[2]);
        cst[ci] = cn;
        const float hv = sigf(g[3])*tanhfast(cn);
        hA[(size_t)b*strideA + offA + cell] = (_Float16)hv;
        if(hB) hB[(size_t)b*strideB + offB + cell] = (_Float16)hv;
        if(hF) hF[(size_t)b*HH + cell] = hv;
    }
}

// q (redundant per b) + energies for a 32-t slice. grid 256: b=bid>>3, ts=bid&7. 256 threads.
__global__ __launch_bounds__(256) void k_qe(
    const float* __restrict__ h2f,      // [32][1024] fp32
    const _Float16* __restrict__ WqT, const float* __restrict__ cbp,
    const float* __restrict__ Mloc, const float* __restrict__ ve,
    const float* __restrict__ awc, const __half* __restrict__ pe,
    float* __restrict__ e_ws)
{
    const int b = blockIdx.x >> 3, ts = blockIdx.x & 7;
    const int t0 = ts*32;
    const int tid = threadIdx.x;
    __shared__ float h2s[1024], qc[256], qf[128], ml[31*AA], ves[AA], awin[64], ep[256];
    for(int i=tid; i<1024; i+=256) h2s[i] = h2f[(size_t)b*HH + i];
    for(int i=tid; i<31*AA; i+=256) ml[i] = Mloc[i];
    if(tid < AA) ves[tid] = ve[tid];
    if(tid < 62){
        const int g = t0 - 15 + tid;
        awin[tid] = (g>=0 && g<TENC) ? awc[b*TENC+g] : 0.f;
    }
    __syncthreads();
    {   // q[a] = h2 . WqT[a][:]
        const int a = tid & 127, tp = tid >> 7;
        float qa = 0.f;
        const _Float16* wq = WqT + (size_t)a*HH + tp*512;
        const float* hs = h2s + tp*512;
        for(int kb=0; kb<512; kb+=8){
            const h8v w8 = *(const h8v*)(wq + kb);
            #pragma unroll
            for(int i2=0;i2<8;i2++) qa = fmaf((float)w8[i2], hs[kb+i2], qa);
        }
        qc[tp*AA + a] = qa;
    }
    __syncthreads();
    if(tid < AA) qf[tid] = qc[tid] + qc[AA+tid] + cbp[tid];
    __syncthreads();
    {   // energies: thread (tl 32, aq 8) covers a-range aq*16..+16 for t0+tl
        const int tl = tid & 31, aq = tid >> 5;
        const int a0 = aq*16;
        const int t  = t0 + tl;
        float s[16];
        const __half* pp = pe + ((size_t)(b*TENC + t))*AA + a0;
        #pragma unroll
        for(int j=0;j<16;j++) s[j] = qf[a0+j] + __half2float(pp[j]);
        for(int d=0;d<31;d++){
            const float w = awin[tl+d];
            #pragma unroll
            for(int j=0;j<16;j++) s[j] = fmaf(w, ml[d*AA + a0 + j], s[j]);
        }
        float es = 0.f;
        #pragma unroll
        for(int j=0;j<16;j++) es = fmaf(tanhfast(s[j]), ves[a0+j], es);
        ep[aq*32 + tl] = es;
    }
    __syncthreads();
    if(tid < 32){
        float e = 0.f;
        #pragma unroll
        for(int q=0;q<8;q++) e += ep[q*32 + tid];
        e_ws[b*TENC + t0 + tid] = e;
    }
}

// softmax + awc + ctx (-> next XS1h row, fp16) + full output projection. grid 32 (b=bid), 256 threads.
__global__ __launch_bounds__(256) void k_attn(
    const float* __restrict__ e_ws, const __half* __restrict__ inputs_h,
    const __half* __restrict__ PIP, float* __restrict__ awc,
    _Float16* __restrict__ XS1hn,      // ctx -> [b][256:768] (row stride K1)
    const float* __restrict__ h2f,     // [32][1024] fp32
    const _Float16* __restrict__ WohT, const float* __restrict__ bp,
    float* __restrict__ out, int t)
{
    const int b = blockIdx.x, tid = threadIdx.x;
    __shared__ float aw[TENC], h2s[1024], red[320], sred[8];
    for(int i=tid; i<1024; i+=256) h2s[i] = h2f[(size_t)b*HH + i];
    const float e = e_ws[b*TENC + tid];
    float m = e;
    #pragma unroll
    for(int o=32;o>=1;o>>=1) m = fmaxf(m, __shfl_xor(m, o));
    if((tid&63)==0) sred[tid>>6] = m;
    __syncthreads();
    m = fmaxf(fmaxf(sred[0],sred[1]), fmaxf(sred[2],sred[3]));
    const float p = __expf(e - m);
    float sum = p;
    #pragma unroll
    for(int o=32;o>=1;o>>=1) sum += __shfl_xor(sum, o);
    if((tid&63)==0) sred[4+(tid>>6)] = sum;
    __syncthreads();
    sum = sred[4]+sred[5]+sred[6]+sred[7];
    const float awv = p/sum;
    aw[tid] = awv;
    awc[b*TENC + tid] += awv;
    __syncthreads();
    // ctx: channels tid and tid+256
    {
        float a0=0.f, a1=0.f;
        const __half* ib = inputs_h + (size_t)b*TENC*EE;
        for(int tt=0; tt<TENC; tt+=4){
            const float4 w4 = *(const float4*)&aw[tt];
            a0 = fmaf(w4.x, __half2float(ib[(size_t)(tt+0)*EE + tid]),       a0);
            a1 = fmaf(w4.x, __half2float(ib[(size_t)(tt+0)*EE + 256 + tid]), a1);
            a0 = fmaf(w4.y, __half2float(ib[(size_t)(tt+1)*EE + tid]),       a0);
            a1 = fmaf(w4.y, __half2float(ib[(size_t)(tt+1)*EE + 256 + tid]), a1);
            a0 = fmaf(w4.z, __half2float(ib[(size_t)(tt+2)*EE + tid]),       a0);
            a1 = fmaf(w4.z, __half2float(ib[(size_t)(tt+2)*EE + 256 + tid]), a1);
            a0 = fmaf(w4.w, __half2float(ib[(size_t)(tt+3)*EE + tid]),       a0);
            a1 = fmaf(w4.w, __half2float(ib[(size_t)(tt+3)*EE + 256 + tid]), a1);
        }
        _Float16* xrow = XS1hn + (size_t)b*K1 + 256;
        xrow[tid]       = (_Float16)a0;
        xrow[256 + tid] = (_Float16)a1;
    }
    // output: s1 = h2 @ WohT (tid<160: m, kh halves of K) then s2 = aw . PIP (same threads)
    if(tid < 160){
        const int m2 = tid % 80, kh = tid / 80;
        float s1 = 0.f;
        const _Float16* wo = WohT + (size_t)m2*HH + kh*512;
        const float* hs = h2s + kh*512;
        for(int kb=0; kb<512; kb+=8){
            const h8v w8 = *(const h8v*)(wo + kb);
            #pragma unroll
            for(int i2=0;i2<8;i2++) s1 = fmaf((float)w8[i2], hs[kb+i2], s1);
        }
        red[kh*80 + m2] = s1;
        float s2 = 0.f;
        const __half* pp = PIP + ((size_t)(b*TENC) + kh*128)*NM + m2;
        const float* awp = aw + kh*128;
        for(int tt=0; tt<128; tt++) s2 = fmaf(awp[tt], __half2float(pp[(size_t)tt*NM]), s2);
        red[160 + kh*80 + m2] = s2;
    }
    __syncthreads();
    if(tid < NM){
        const float o = red[tid] + red[80+tid] + red[160+tid] + red[240+tid] + bp[tid];
        out[((size_t)t*BB + b)*NM + tid] = o;
    }
}

// ---------------- host ----------------

extern "C" void kernel_launch(void* const* d_in, const int* in_sizes, int n_in,
                              void* d_out, int out_size, void* d_ws, size_t ws_size,
                              hipStream_t stream)
{
    const float* inputs = (const float*)d_in[0];
    const float* pmels  = (const float*)d_in[1];
    const float* W_enc  = (const float*)d_in[2];
    const float* W_q    = (const float*)d_in[3];
    const float* conv_w = (const float*)d_in[4];
    const float* conv_b = (const float*)d_in[5];
    const float* W_loc  = (const float*)d_in[6];
    const float* v_e    = (const float*)d_in[7];
    const float* pw1    = (const float*)d_in[8];
    const float* pb1    = (const float*)d_in[9];
    const float* pw2    = (const float*)d_in[10];
    const float* pb2    = (const float*)d_in[11];
    const float* Wi1    = (const float*)d_in[12];
    const float* Wh1    = (const float*)d_in[13];
    const float* bl1    = (const float*)d_in[14];
    const float* Wi2    = (const float*)d_in[15];
    const float* Wh2    = (const float*)d_in[16];
    const float* bl2    = (const float*)d_in[17];
    const float* Wp     = (const float*)d_in[18];
    const float* bp     = (const float*)d_in[19];
    float* out = (float*)d_out;
    (void)in_sizes; (void)n_in; (void)out_size; (void)ws_size;

    char* ws = (char*)d_ws;
    size_t off = 0;
    auto carve = [&](size_t bytes)->char* {
        char* p = ws + off;
        off += (bytes + 255) & ~(size_t)255;
        return p;
    };
    __half*    inputs_h = (__half*)   carve((size_t)BB*TENC*EE*2);
    __half*    pe_h     = (__half*)   carve((size_t)BB*TENC*AA*2);
    __half*    PIP      = (__half*)   carve((size_t)BB*TENC*NM*2);
    _Float16*  XS1h     = (_Float16*) carve((size_t)(TDEC+1)*BB*K1*2);
    _Float16*  XS2h     = (_Float16*) carve((size_t)2*BB*K2*2);
    _Float16*  WA       = (_Float16*) carve((size_t)GG*K2*2);   // W2T, later reused as W1F
    _Float16*  WB       = (_Float16*) carve((size_t)GG*K1*2);   // W1T
    _Float16*  W2F      = (_Float16*) carve((size_t)GG*K2*2);
    _Float16*  WqT      = (_Float16*) carve((size_t)AA*HH*2);
    _Float16*  WohT     = (_Float16*) carve((size_t)NM*HH*2);
    // zeroed block: c1 | c2 | awc
    const int NZ = HH*BB + HH*BB + BB*TENC;   // 32768+32768+8192
    float* zblk = (float*)carve((size_t)NZ*4);
    float* c1  = zblk;
    float* c2  = c1 + HH*BB;
    float* awc = c2 + HH*BB;
    float* h2f  = (float*)carve((size_t)BB*HH*4);
    float* e_ws = (float*)carve((size_t)BB*TENC*4);
    float* Mloc = (float*)carve((size_t)31*AA*4);
    float* cbp  = (float*)carve((size_t)AA*4);
    _Float16* W1F = WA;   // alias: W2T dead once W2F is built

    // ---- one-time precompute (per launch) ----
    k_zero<<<(NZ+255)/256,256,0,stream>>>(zblk, NZ);
    k_zero<<<(2*BB*K2/2+255)/256,256,0,stream>>>((float*)XS2h, 2*BB*K2/2);      // h1,h2 = 0 (fp16 zero bits)
    k_zero<<<(BB*K1/2+255)/256,256,0,stream>>>((float*)XS1h, BB*K1/2);          // row t=0
    k_cvt_half<<<2048,256,0,stream>>>(inputs, inputs_h, BB*TENC*EE);
    k_proc_enc<<<BB*TENC,128,0,stream>>>(inputs, W_enc, pe_h);
    k_prenet<<<TDEC,256,0,stream>>>(pmels, pw1,pb1,pw2,pb2, XS1h);
    k_mloc<<<1,128,0,stream>>>(conv_w, conv_b, W_loc, Mloc, cbp);
    // W2 -> WA (packed [p][K2]) -> W2F (fragment order); then W1 -> WB -> W1F (=WA, now dead)
    k_transpose2<<<dim3(GG/32, 1024/32),256,0,stream>>>(Wi2, WA, 1024, GG, K2, 0,    1);
    k_transpose2<<<dim3(GG/32, 1024/32),256,0,stream>>>(Wh2, WA, 1024, GG, K2, 1024, 1);
    k_wfrag<<<dim3(K2/128, GG/16),256,0,stream>>>(WA, W2F, K2);
    k_transpose2<<<dim3(GG/32,  768/32),256,0,stream>>>(Wi1, WB, 768,  GG, K1, 0,    1);
    k_transpose2<<<dim3(GG/32, 1024/32),256,0,stream>>>(Wh1, WB, 1024, GG, K1, 768,  1);
    k_wfrag<<<dim3(K1/128, GG/16),256,0,stream>>>(WB, W1F, K1);
    k_transpose2<<<dim3(AA/32, 1024/32),256,0,stream>>>(W_q, WqT, 1024, AA, HH, 0,   0);
    k_transpose2<<<dim3(3,     1024/32),256,0,stream>>>(Wp,  WohT, 1024, NM, HH, 0,  0);
    k_pip<<<BB*64,320,0,stream>>>(inputs, Wp + (size_t)HH*NM, PIP);

    // ---- sequential decode: 4 kernels/step ----
    for(int t=0; t<TDEC; t++){
        const int p = t & 1;
        _Float16* x1c = XS1h + (size_t)t*BB*K1;
        _Float16* x1n = XS1h + (size_t)(t+1)*BB*K1;
        _Float16* x2p = XS2h + (size_t)p*BB*K2;
        _Float16* x2n = XS2h + (size_t)(1-p)*BB*K2;

        k_lstm_mfma<K1><<<256,512,0,stream>>>(x1c, W1F, bl1, c1,
                                              x2p, K2, 0,        // h1 -> XS2h[p][b][0:1024]
                                              x1n, K1, 768,      // h1 -> next XS1h row
                                              (float*)nullptr);
        k_lstm_mfma<K2><<<256,512,0,stream>>>(x2p, W2F, bl2, c2,
                                              x2n, K2, 1024,     // h2 -> XS2h[1-p][b][1024:2048]
                                              (_Float16*)nullptr, 0, 0,
                                              h2f);              // h2 fp32 for qe/attn
        k_qe<<<256,256,0,stream>>>(h2f, WqT, cbp, Mloc, v_e, awc, pe_h, e_ws);
        k_attn<<<BB,256,0,stream>>>(e_ws, inputs_h, PIP, awc, x1n, h2f,
                                    WohT, bp, out, t);
    }
}